// Round 16
// baseline (284.917 us; speedup 1.0000x reference)
//
#include <hip/hip_runtime.h>
#include <math.h>

#define SS 2048
#define DD 1024
#define HH 16

typedef _Float16 f16;
typedef _Float16 half8 __attribute__((ext_vector_type(8)));
typedef _Float16 half4 __attribute__((ext_vector_type(4)));
typedef float f32x4 __attribute__((ext_vector_type(4)));
typedef unsigned long long u64;

#define LOG2E 1.44269504f
#define MASKNEG -30000.0f

__device__ __forceinline__ void gload16(const void* g, void* lds) {
    __builtin_amdgcn_global_load_lds(
        (const __attribute__((address_space(1))) unsigned int*)g,
        (__attribute__((address_space(3))) unsigned int*)lds, 16, 0, 0);
}

// ============================================================
// fused prep A: cvt_x (q/k/v f32->f16, 6144 blocks) + cvt_wT
// (weight transpose+cast, 1024 blocks). Independent work, one launch.
// ============================================================
__global__ __launch_bounds__(256)
void prep_xw(const float* __restrict__ q, const float* __restrict__ k,
             const float* __restrict__ v, f16* __restrict__ oq,
             f16* __restrict__ ok, f16* __restrict__ ov,
             const float* __restrict__ wq, const float* __restrict__ wk,
             const float* __restrict__ wv, const float* __restrict__ wo,
             f16* __restrict__ owq, f16* __restrict__ owk,
             f16* __restrict__ owv, f16* __restrict__ owo)
{
    __shared__ __align__(16) char smem[16640];
    const int bid = blockIdx.x;
    const int t = threadIdx.x;
    if (bid < 6144) {
        const int z = bid / 2048, bx = bid % 2048;
        const float* src = z == 0 ? q : z == 1 ? k : v;
        f16* dst = z == 0 ? oq : z == 1 ? ok : ov;
        size_t i = ((size_t)bx * 256 + t) * 8;
        float4 v0 = *reinterpret_cast<const float4*>(src + i);
        float4 v1 = *reinterpret_cast<const float4*>(src + i + 4);
        half8 h;
        h[0] = (f16)v0.x; h[1] = (f16)v0.y; h[2] = (f16)v0.z; h[3] = (f16)v0.w;
        h[4] = (f16)v1.x; h[5] = (f16)v1.y; h[6] = (f16)v1.z; h[7] = (f16)v1.w;
        *reinterpret_cast<half8*>(dst + i) = h;
    } else {
        const int r = bid - 6144;
        const int z = r / 256;
        const int bx = r % 16, by = (r / 16) % 16;
        const float* W = z == 0 ? wq : z == 1 ? wk : z == 2 ? wv : wo;
        f16* WT = z == 0 ? owq : z == 1 ? owk : z == 2 ? owv : owo;
        float (*Lt)[65] = (float (*)[65])smem;
        const int n0 = bx * 64, k0 = by * 64;
        {
            int row = t >> 2;
            int c0  = (t & 3) * 16;
#pragma unroll
            for (int u = 0; u < 4; ++u) {
                float4 x = *reinterpret_cast<const float4*>(
                    &W[(size_t)(k0 + row) * DD + n0 + c0 + u * 4]);
                Lt[row][c0 + u * 4 + 0] = x.x;
                Lt[row][c0 + u * 4 + 1] = x.y;
                Lt[row][c0 + u * 4 + 2] = x.z;
                Lt[row][c0 + u * 4 + 3] = x.w;
            }
        }
        __syncthreads();
        {
            int n  = t >> 2;
            int kc = (t & 3) * 16;
            half8 h0, h1;
#pragma unroll
            for (int u = 0; u < 8; ++u) h0[u] = (f16)Lt[kc + u][n];
#pragma unroll
            for (int u = 0; u < 8; ++u) h1[u] = (f16)Lt[kc + 8 + u][n];
            f16* dst = &WT[(size_t)(n0 + n) * DD + k0 + kc];
            *reinterpret_cast<half8*>(dst) = h0;
            *reinterpret_cast<half8*>(dst + 8) = h1;
        }
    }
}

// ============================================================
// fused prep B bodies: proj3 / rpbT3 / maskbits
// ============================================================
// proj3, SOFTWARE-PIPELINED (R6 attn pattern): next K-tile is loaded
// into REGISTERS before the MFMA phase; the commit (ds_write, where the
// compiler's vmcnt wait lands) happens AFTER the MFMA phase — load
// latency is hidden under compute instead of drained at the barrier.
// Single 32 KB LDS buffer, 2 barriers/iter (same count as before).
// Epilogue: LDS-transposed coalesced half8 stores (R15).
__device__ void proj3_body(char* smem, int gx, int gy, int gz,
                           const f16* Xq, const f16* Xk, const f16* Xv,
                           const f16* WqT, const f16* WkT, const f16* WvT,
                           const float* bq, const float* bk, const float* bv,
                           f16* Qo, f16* Ko, f16* VTo)
{
    char* AsB = smem;
    char* BsB = smem + 128 * 64 * 2;
    const int t = threadIdx.x, wid = t >> 6, l = t & 63, c = l & 15, g = l >> 4;
    const f16 *Ap, *Bp; const float* bias; int m0, n0;
    if (gz == 2) { Ap = WvT; Bp = Xv; bias = bv; m0 = gx * 128; n0 = gy * 128; }
    else if (gz == 1) { Ap = Xk; Bp = WkT; bias = bk; m0 = gy * 128; n0 = gx * 128; }
    else { Ap = Xq; Bp = WqT; bias = bq; m0 = gy * 128; n0 = gx * 128; }
    const int wm = wid >> 1, wn = wid & 1;
    f32x4 acc[4][4] = {};

    // staging geometry: thread covers rows r0+{0,8,16,24}, 16B chunk s
    const int s  = l & 7;
    const int r0 = wid * 32 + (l >> 3);
    const int sdst = (s << 4) ^ ((r0 & 7) << 4);   // j-invariant (r0&7 == row&7)

    half8 aN[4], bN[4];
    // prologue: tile k0=0 -> regs -> LDS
#pragma unroll
    for (int j = 0; j < 4; ++j) {
        int row = r0 + j * 8;
        aN[j] = *(const half8*)(Ap + (size_t)(m0 + row) * DD + s * 8);
        bN[j] = *(const half8*)(Bp + (size_t)(n0 + row) * DD + s * 8);
    }
#pragma unroll
    for (int j = 0; j < 4; ++j) {
        int row = r0 + j * 8;
        *(half8*)(AsB + row * 128 + sdst) = aN[j];
        *(half8*)(BsB + row * 128 + sdst) = bN[j];
    }
    __syncthreads();

    for (int k0 = 0; k0 < DD; k0 += 64) {
        const bool more = (k0 + 64 < DD);
        const int kn = more ? k0 + 64 : 0;
        // issue next-tile loads (registers; latency hidden by MFMA phase)
#pragma unroll
        for (int j = 0; j < 4; ++j) {
            int row = r0 + j * 8;
            aN[j] = *(const half8*)(Ap + (size_t)(m0 + row) * DD + kn + s * 8);
            bN[j] = *(const half8*)(Bp + (size_t)(n0 + row) * DD + kn + s * 8);
        }
        // MFMA phase on current LDS tile
#pragma unroll
        for (int ks = 0; ks < 2; ++ks) {
            half8 af[4];
#pragma unroll
            for (int mt = 0; mt < 4; ++mt) {
                int row = wm * 64 + mt * 16 + c;
                af[mt] = *(const half8*)(AsB + row * 128 +
                         ((ks * 64 + g * 16) ^ ((row & 7) << 4)));
            }
#pragma unroll
            for (int nt = 0; nt < 4; ++nt) {
                int row = wn * 64 + nt * 16 + c;
                half8 bf = *(const half8*)(BsB + row * 128 +
                           ((ks * 64 + g * 16) ^ ((row & 7) << 4)));
#pragma unroll
                for (int mt = 0; mt < 4; ++mt)
                    acc[mt][nt] = __builtin_amdgcn_mfma_f32_16x16x32_f16(
                        af[mt], bf, acc[mt][nt], 0, 0, 0);
            }
        }
        __syncthreads();          // all MFMA reads of this tile done
        if (more) {
#pragma unroll
            for (int j = 0; j < 4; ++j) {   // vmcnt waits land here
                int row = r0 + j * 8;
                *(half8*)(AsB + row * 128 + sdst) = aN[j];
                *(half8*)(BsB + row * 128 + sdst) = bN[j];
            }
        }
        __syncthreads();          // commit visible for next iteration
    }

    // ---- epilogue: bias + convert, stash to LDS [row][col^swz] ----
    f16* Ls = (f16*)smem;                  // [128][128] f16 = 32 KB
    const float post = (gz == 0) ? 0.125f * LOG2E : 1.0f;
    if (gz < 2) {
#pragma unroll
        for (int nt = 0; nt < 4; ++nt) {
            int col = wn * 64 + nt * 16 + c;
            float bn = bias[n0 + col];
#pragma unroll
            for (int mt = 0; mt < 4; ++mt)
#pragma unroll
                for (int reg = 0; reg < 4; ++reg) {
                    int row = wm * 64 + mt * 16 + 4 * g + reg;
                    Ls[row * 128 + (col ^ ((row & 7) << 3))] =
                        (f16)((acc[mt][nt][reg] + bn) * post);
                }
        }
    } else {
#pragma unroll
        for (int mt = 0; mt < 4; ++mt)
#pragma unroll
            for (int reg = 0; reg < 4; ++reg) {
                int row = wm * 64 + mt * 16 + 4 * g + reg;
                float bd = bias[m0 + row];
#pragma unroll
                for (int nt = 0; nt < 4; ++nt) {
                    int col = wn * 64 + nt * 16 + c;
                    Ls[row * 128 + (col ^ ((row & 7) << 3))] =
                        (f16)(acc[mt][nt][reg] + bd);
                }
            }
    }
    __syncthreads();
    // ---- read 16-B runs, store coalesced half8 ----
#pragma unroll
    for (int e = 0; e < 8; ++e) {
        int fi = e * 256 + t;
        int row = fi >> 4;
        int col0 = (fi & 15) * 8;
        half8 v = *reinterpret_cast<const half8*>(
            Ls + row * 128 + (col0 ^ ((row & 7) << 3)));
        if (gz < 2) {
            f16* dst = gz ? Ko : Qo;
            int m = m0 + row, n = n0 + col0;
            int b = m >> 11, sdx = m & (SS - 1);
            int h = n >> 6, hd = n & 63;
            *reinterpret_cast<half8*>(
                &dst[(((size_t)(b * HH + h)) * SS + sdx) * 64 + hd]) = v;
        } else {
            int m = m0 + row, n = n0 + col0;
            int h = m >> 6, dl = m & 63;
            int b = n >> 11;
            *reinterpret_cast<half8*>(
                &VTo[(((size_t)(b * HH + h)) * 64 + dl) * SS + (n & (SS - 1))]) = v;
        }
    }
}

// rpb[j][i][h] f32 -> rpbT[h][i][j'] f16 (scaled log2e), j' permuted
// within each 64-block; [16][16][64] XOR-swizzled tile = exactly 32 KB.
__device__ void rpbT3_body(char* smem, int gxi, int gyj,
                           const float* rpb, f16* rpbT)
{
    f16* Lt = (f16*)smem;                 // flat [16 h][16 i][64 j-swz]
    const int t = threadIdx.x, wid = t >> 6, l = t & 63;
    const int i0 = gxi * 16;
    const int j0 = gyj * 64;
    const int il = l >> 2;
    const int h0 = (l & 3) * 4;
    const int swz = (il & 7) << 3;
#pragma unroll
    for (int p = 0; p < 16; ++p) {
        int jl = p * 4 + wid;
        float4 v = *reinterpret_cast<const float4*>(
            rpb + ((size_t)(j0 + jl) * SS + i0 + il) * HH + h0);
        int js = jl ^ swz;
        Lt[((h0 + 0) * 16 + il) * 64 + js] = (f16)(v.x * LOG2E);
        Lt[((h0 + 1) * 16 + il) * 64 + js] = (f16)(v.y * LOG2E);
        Lt[((h0 + 2) * 16 + il) * 64 + js] = (f16)(v.z * LOG2E);
        Lt[((h0 + 3) * 16 + il) * 64 + js] = (f16)(v.w * LOG2E);
    }
    __syncthreads();
    const int part = t & 7;
#pragma unroll
    for (int p = 0; p < 8; ++p) {
        int rowid = p * 32 + (t >> 3);
        int h = rowid >> 4, i2 = rowid & 15;
        int rsw = (i2 & 7) << 3;
        const f16* rowp = Lt + (h * 16 + i2) * 64;
        half8 v;
#pragma unroll
        for (int e = 0; e < 8; ++e) {
            int sig = 32 * (part & 1) + 16 * (e >> 2) + 4 * (part >> 1) + (e & 3);
            v[e] = rowp[sig ^ rsw];
        }
        *reinterpret_cast<half8*>(
            rpbT + ((size_t)h * SS + i0 + i2) * SS + j0 + part * 8) = v;
    }
}

__device__ void maskbits_body(int gx, const int* mask, u64* mb)
{
    const int t = threadIdx.x, wid = t >> 6, l = t & 63;
    const int row = gx * 4 + wid;     // b*SS+i
    const int* src = mask + (size_t)row * SS;
    u64* dst = mb + (size_t)row * 32;
    for (int it = 0; it < 32; ++it) {
        int mv = src[it * 64 + l];
        u64 bal = __ballot(mv != 0);
        if (l == 0) dst[it] = bal;
    }
}

// fused prep B: proj3 (768, spread uniformly) + rpbT3 (4096) +
// maskbits (1024) = 5888 blocks. Union LDS exactly 32 KB.
__global__ __launch_bounds__(256)
void prep_big(const f16* __restrict__ Xq, const f16* __restrict__ Xk,
              const f16* __restrict__ Xv, const f16* __restrict__ WqT,
              const f16* __restrict__ WkT, const f16* __restrict__ WvT,
              const float* __restrict__ bq, const float* __restrict__ bk,
              const float* __restrict__ bv,
              f16* __restrict__ Qo, f16* __restrict__ Ko, f16* __restrict__ VTo,
              const float* __restrict__ rpb, f16* __restrict__ rpbT,
              const int* __restrict__ mask, u64* __restrict__ mbits)
{
    __shared__ __align__(16) char smem[32768];
    const int bid = blockIdx.x;
    const int pid0 = (int)(((long long)bid * 768) / 5888);
    const int pid1 = (int)(((long long)(bid + 1) * 768) / 5888);
    if (pid1 != pid0) {
        proj3_body(smem, pid0 % 8, (pid0 / 8) % 32, pid0 / 256,
                   Xq, Xk, Xv, WqT, WkT, WvT, bq, bk, bv, Qo, Ko, VTo);
    } else {
        const int mid = bid - pid0;
        if (mid < 4096)
            rpbT3_body(smem, mid % 128, mid / 128, rpb, rpbT);
        else
            maskbits_body(mid - 4096, mask, mbits);
    }
}

// ============================================================
// Flash attention (R8/R10 version): swapped QK^T, lane-local softmax,
// in-register P, QBLK=64, 4 blocks/CU, one barrier/iter. LDS 32 KB.
// ============================================================
__global__ __launch_bounds__(256, 4)
void attn_fwd(const f16* __restrict__ Qw, const f16* __restrict__ Kw,
              const f16* __restrict__ VTw, const f16* __restrict__ rpbT,
              const u64* __restrict__ mbits, f16* __restrict__ AOh)
{
    __shared__ f16 Ks[2][64 * 64];
    __shared__ f16 Vs[2][64 * 64];

    const int t = threadIdx.x, wid = t >> 6, l = t & 63, c = l & 15, g = l >> 4;
    const int bh = blockIdx.x, b = bh >> 4, h = bh & 15;
    const int q0 = blockIdx.y * 64;
    const size_t baseSD = (size_t)bh * SS * 64;
    const size_t baseDS = (size_t)bh * 64 * SS;
    const f16* Kbase = Kw + baseSD;
    const f16* Vbase = VTw + baseDS;

    const int qrow_c = q0 + wid * 16 + c;            // this lane's softmax row
    const f16* bp = rpbT + (size_t)h * SS * SS + (size_t)qrow_c * SS + g * 16;
    const u64* mp = mbits + ((size_t)b * SS + qrow_c) * 32;

    const int s     = l & 7;
    const int srow0 = wid * 16 + (l >> 3);
    const int sswz  = (srow0 & 7) << 4;
    const int kdst  = (s << 4) ^ sswz;
    const int velo  = 32 * (s >> 2) + 16 * (s & 1) + 4 * ((s >> 1) & 1);
    const int vdlo  = (velo * 2) ^ sswz;
    const int vdhi  = (velo * 2 + 16) ^ sswz;

    int ga[4];
#pragma unroll
    for (int r = 0; r < 4; ++r) ga[r] = (g * 4 + r) * 4;

    half8 qf[2];
    qf[0] = *(const half8*)(Qw + baseSD + (size_t)qrow_c * 64 + g * 8);
    qf[1] = *(const half8*)(Qw + baseSD + (size_t)qrow_c * 64 + 32 + g * 8);

    // ---- prologue: stage tile 0 ----
    {
        half8 k0 = *(const half8*)(Kbase + (size_t)srow0 * 64 + s * 8);
        half8 k1 = *(const half8*)(Kbase + (size_t)(srow0 + 8) * 64 + s * 8);
        half8 v0 = *(const half8*)(Vbase + (size_t)srow0 * SS + s * 8);
        half8 v1 = *(const half8*)(Vbase + (size_t)(srow0 + 8) * SS + s * 8);
        char* kd = (char*)Ks[0]; char* vd = (char*)Vs[0];
        *(half8*)(kd + srow0 * 128 + kdst) = k0;
        *(half8*)(kd + (srow0 + 8) * 128 + kdst) = k1;
        half4 lo0 = {v0[0], v0[1], v0[2], v0[3]}, hi0 = {v0[4], v0[5], v0[6], v0[7]};
        half4 lo1 = {v1[0], v1[1], v1[2], v1[3]}, hi1 = {v1[4], v1[5], v1[6], v1[7]};
        *(half4*)(vd + srow0 * 128 + vdlo) = lo0;
        *(half4*)(vd + srow0 * 128 + vdhi) = hi0;
        *(half4*)(vd + (srow0 + 8) * 128 + vdlo) = lo1;
        *(half4*)(vd + (srow0 + 8) * 128 + vdhi) = hi1;
    }
    half8 bb0 = *(const half8*)(bp);
    half8 bb1 = *(const half8*)(bp + 8);
    u64 mm = mp[0];
    __syncthreads();

    f32x4 acc[4] = {};
    float mrow = -INFINITY, lp = 0.f;
    const int shg = 4 * g;

    int buf = 0;
    for (int kt = 0; kt < SS / 64; ++kt) {
        const bool more = (kt + 1 < SS / 64);
        const int jn = more ? (kt + 1) * 64 : 0;
        const int ktn = more ? kt + 1 : 0;

        half8 k0n = *(const half8*)(Kbase + (size_t)(jn + srow0) * 64 + s * 8);
        half8 k1n = *(const half8*)(Kbase + (size_t)(jn + srow0 + 8) * 64 + s * 8);
        half8 v0n = *(const half8*)(Vbase + (size_t)srow0 * SS + jn + s * 8);
        half8 v1n = *(const half8*)(Vbase + (size_t)(srow0 + 8) * SS + jn + s * 8);
        half8 bbn0 = *(const half8*)(bp + jn);
        half8 bbn1 = *(const half8*)(bp + jn + 8);
        u64 mmn = mp[ktn];

        char* KsB = (char*)Ks[buf];
        char* VsB = (char*)Vs[buf];

        // ---- C-init: sc = mask ? bias : MASKNEG  (log2-domain)
        u64 sh = mm >> shg;
        f32x4 sc[4];
#pragma unroll
        for (int nt = 0; nt < 4; ++nt)
#pragma unroll
            for (int r = 0; r < 4; ++r) {
                float bf = (float)(nt < 2 ? bb0[nt * 4 + r] : bb1[(nt - 2) * 4 + r]);
                sc[nt][r] = ((sh >> (16 * nt + r)) & 1) ? bf : MASKNEG;
            }

        // ---- QK^T swapped
        __builtin_amdgcn_s_setprio(1);
#pragma unroll
        for (int ks = 0; ks < 2; ++ks)
#pragma unroll
            for (int nt = 0; nt < 4; ++nt) {
                int row = nt * 16 + c;
                half8 kf = *(const half8*)(KsB + row * 128 +
                           ((ks * 64 + g * 16) ^ ((row & 7) << 4)));
                sc[nt] = __builtin_amdgcn_mfma_f32_16x16x32_f16(
                    kf, qf[ks], sc[nt], 0, 0, 0);
            }
        __builtin_amdgcn_s_setprio(0);

        // ---- lane-local softmax (base 2) with defer-max
        float rm = fmaxf(fmaxf(fmaxf(sc[0][0], sc[0][1]), fmaxf(sc[0][2], sc[0][3])),
                         fmaxf(fmaxf(sc[1][0], sc[1][1]), fmaxf(sc[1][2], sc[1][3])));
        rm = fmaxf(rm, fmaxf(fmaxf(fmaxf(sc[2][0], sc[2][1]), fmaxf(sc[2][2], sc[2][3])),
                             fmaxf(fmaxf(sc[3][0], sc[3][1]), fmaxf(sc[3][2], sc[3][3]))));
        rm = fmaxf(rm, __shfl_xor(rm, 16));
        rm = fmaxf(rm, __shfl_xor(rm, 32));
        if (!__all(rm <= mrow + 8.0f)) {
            float mn = fmaxf(mrow, rm);
            float scal = exp2f(mrow - mn);
            mrow = mn;
            lp *= scal;
            float sq[4];
#pragma unroll
            for (int r = 0; r < 4; ++r)
                sq[r] = __int_as_float(__builtin_amdgcn_ds_bpermute(
                            ga[r], __float_as_int(scal)));
#pragma unroll
            for (int nt = 0; nt < 4; ++nt)
#pragma unroll
                for (int r = 0; r < 4; ++r) acc[nt][r] *= sq[r];
        }
        float psum = 0.f;
#pragma unroll
        for (int nt = 0; nt < 4; ++nt)
#pragma unroll
            for (int r = 0; r < 4; ++r) {
                float p = exp2f(sc[nt][r] - mrow);
                sc[nt][r] = p;
                psum += p;
            }
        lp += psum;

        // ---- pack P in-register
        half4 pa[4];
#pragma unroll
        for (int kk = 0; kk < 4; ++kk) {
            half4 pv = {(f16)sc[kk][0], (f16)sc[kk][1],
                        (f16)sc[kk][2], (f16)sc[kk][3]};
            pa[kk] = pv;
        }

        // ---- PV via 16x16x16, b128 V reads
        __builtin_amdgcn_s_setprio(1);
#pragma unroll
        for (int ks = 0; ks < 2; ++ks)
#pragma unroll
            for (int nt2 = 0; nt2 < 4; ++nt2) {
                int row = nt2 * 16 + c;
                half8 vf = *(const half8*)(VsB + row * 128 +
                           ((ks * 64 + g * 16) ^ ((row & 7) << 4)));
                half4 vlo = {vf[0], vf[1], vf[2], vf[3]};
                half4 vhi = {vf[4], vf[5], vf[6], vf[7]};
                acc[nt2] = __builtin_amdgcn_mfma_f32_16x16x16f16(
                    pa[2 * ks], vlo, acc[nt2], 0, 0, 0);
                acc[nt2] = __builtin_amdgcn_mfma_f32_16x16x16f16(
                    pa[2 * ks + 1], vhi, acc[nt2], 0, 0, 0);
            }
        __builtin_amdgcn_s_setprio(0);

        // ---- commit next tile (vmcnt wait lands here, after compute)
        if (more) {
            char* kd = (char*)Ks[buf ^ 1];
            char* vd = (char*)Vs[buf ^ 1];
            *(half8*)(kd + srow0 * 128 + kdst) = k0n;
            *(half8*)(kd + (srow0 + 8) * 128 + kdst) = k1n;
            half4 lo0 = {v0n[0], v0n[1], v0n[2], v0n[3]}, hi0 = {v0n[4], v0n[5], v0n[6], v0n[7]};
            half4 lo1 = {v1n[0], v1n[1], v1n[2], v1n[3]}, hi1 = {v1n[4], v1n[5], v1n[6], v1n[7]};
            *(half4*)(vd + srow0 * 128 + vdlo) = lo0;
            *(half4*)(vd + srow0 * 128 + vdhi) = hi0;
            *(half4*)(vd + (srow0 + 8) * 128 + vdlo) = lo1;
            *(half4*)(vd + (srow0 + 8) * 128 + vdhi) = hi1;
            buf ^= 1;
            bb0 = bbn0; bb1 = bbn1; mm = mmn;
        }
        __syncthreads();
    }

    // ---- epilogue
    float lt = lp;
    lt += __shfl_xor(lt, 16);
    lt += __shfl_xor(lt, 32);
    float linv[4];
#pragma unroll
    for (int r = 0; r < 4; ++r)
        linv[r] = 1.0f / __int_as_float(__builtin_amdgcn_ds_bpermute(
                      ga[r], __float_as_int(lt)));
#pragma unroll
    for (int r = 0; r < 4; ++r) {
        int qrow = q0 + wid * 16 + 4 * g + r;
#pragma unroll
        for (int nt2 = 0; nt2 < 4; ++nt2)
            AOh[((size_t)b * SS + qrow) * DD + h * 64 + nt2 * 16 + c] =
                (f16)(acc[nt2][r] * linv[r]);
    }
}

// ============================================================
// Output projection: out(f32) = AO(f16) @ Wo + bo.
// ============================================================
__global__ __launch_bounds__(256)
void gemm_out(const f16* __restrict__ A, const f16* __restrict__ BT,
              const float* __restrict__ bias, float* __restrict__ out)
{
    __shared__ f16 As[128 * 64];
    __shared__ f16 Bs[128 * 64];
    const int t = threadIdx.x, wid = t >> 6, l = t & 63, c = l & 15, g = l >> 4;
    const int m0 = blockIdx.y * 128, n0 = blockIdx.x * 128;
    const int wm = wid >> 1, wn = wid & 1;
    f32x4 acc[4][4] = {};
    char* AsB = (char*)As; char* BsB = (char*)Bs;

    for (int k0 = 0; k0 < DD; k0 += 64) {
        __syncthreads();
#pragma unroll
        for (int j = 0; j < 4; ++j) {
            int row = wid * 32 + j * 8 + (l >> 3);
            int slot = (l & 7) ^ (row & 7);
            gload16(A + (size_t)(m0 + row) * DD + k0 + slot * 8,
                    AsB + (wid * 32 + j * 8) * 128);
            gload16(BT + (size_t)(n0 + row) * DD + k0 + slot * 8,
                    BsB + (wid * 32 + j * 8) * 128);
        }
        __syncthreads();
#pragma unroll
        for (int ks = 0; ks < 2; ++ks) {
            half8 af[4];
#pragma unroll
            for (int mt = 0; mt < 4; ++mt) {
                int row = wm * 64 + mt * 16 + c;
                af[mt] = *(const half8*)(AsB + row * 128 +
                         ((ks * 64 + g * 16) ^ ((row & 7) << 4)));
            }
#pragma unroll
            for (int nt = 0; nt < 4; ++nt) {
                int row = wn * 64 + nt * 16 + c;
                half8 bf = *(const half8*)(BsB + row * 128 +
                           ((ks * 64 + g * 16) ^ ((row & 7) << 4)));
#pragma unroll
                for (int mt = 0; mt < 4; ++mt)
                    acc[mt][nt] = __builtin_amdgcn_mfma_f32_16x16x32_f16(
                        af[mt], bf, acc[mt][nt], 0, 0, 0);
            }
        }
    }
#pragma unroll
    for (int nt = 0; nt < 4; ++nt) {
        int n = n0 + wn * 64 + nt * 16 + c;
        float bn = bias[n];
#pragma unroll
        for (int mt = 0; mt < 4; ++mt)
#pragma unroll
            for (int reg = 0; reg < 4; ++reg) {
                int m = m0 + wm * 64 + mt * 16 + 4 * g + reg;
                out[(size_t)m * DD + n] = acc[mt][nt][reg] + bn;
            }
    }
}

extern "C" void kernel_launch(void* const* d_in, const int* in_sizes, int n_in,
                              void* d_out, int out_size, void* d_ws, size_t ws_size,
                              hipStream_t stream)
{
    (void)in_sizes; (void)n_in; (void)out_size; (void)ws_size;

    const float* query = (const float*)d_in[0];
    const float* key   = (const float*)d_in[1];
    const float* value = (const float*)d_in[2];
    const int*   mask  = (const int*)d_in[3];
    const float* rpb   = (const float*)d_in[4];
    const float* Wq = (const float*)d_in[5];  const float* bq = (const float*)d_in[6];
    const float* Wk = (const float*)d_in[7];  const float* bk = (const float*)d_in[8];
    const float* Wv = (const float*)d_in[9];  const float* bv = (const float*)d_in[10];
    const float* Wo = (const float*)d_in[11]; const float* bo = (const float*)d_in[12];
    float* out = (float*)d_out;

    // workspace layout (f16 elements). AOh aliases Xq (dead after prep_big).
    const size_t NX = (size_t)2 * SS * DD;   // 4096x1024
    const size_t NW = (size_t)DD * DD;       // 1024x1024
    f16* Xq    = (f16*)d_ws;
    f16* Xk    = Xq + NX;
    f16* Xv    = Xk + NX;
    f16* WqT   = Xv + NX;
    f16* WkT   = WqT + NW;
    f16* WvT   = WkT + NW;
    f16* WoT   = WvT + NW;
    f16* Qw    = WoT + NW;
    f16* Kw    = Qw + NX;
    f16* VTw   = Kw + NX;
    f16* rpbT  = VTw + NX;                   // 16*2048*2048 f16 = 128 MB
    u64* mbits = (u64*)(rpbT + (size_t)HH * SS * SS);  // 1 MB
    f16* AOh   = Xq;   // alias

    prep_xw<<<dim3(7168), 256, 0, stream>>>(query, key, value, Xq, Xk, Xv,
                                            Wq, Wk, Wv, Wo, WqT, WkT, WvT, WoT);
    prep_big<<<dim3(5888), 256, 0, stream>>>(Xq, Xk, Xv, WqT, WkT, WvT,
                                             bq, bk, bv, Qw, Kw, VTw,
                                             rpb, rpbT, mask, mbits);
    attn_fwd<<<dim3(2 * HH, SS / 64), 256, 0, stream>>>(Qw, Kw, VTw, rpbT, mbits, AOh);
    gemm_out<<<dim3(8, 32), 256, 0, stream>>>(AOh, WoT, bo, out);
}

// Round 17
// 276.816 us; speedup vs baseline: 1.0293x; 1.0293x over previous
//
#include <hip/hip_runtime.h>
#include <math.h>

#define SS 2048
#define DD 1024
#define HH 16

typedef _Float16 f16;
typedef _Float16 half8 __attribute__((ext_vector_type(8)));
typedef _Float16 half4 __attribute__((ext_vector_type(4)));
typedef float f32x4 __attribute__((ext_vector_type(4)));
typedef unsigned long long u64;

#define LOG2E 1.44269504f
#define MASKNEG -30000.0f

__device__ __forceinline__ void gload16(const void* g, void* lds) {
    __builtin_amdgcn_global_load_lds(
        (const __attribute__((address_space(1))) unsigned int*)g,
        (__attribute__((address_space(3))) unsigned int*)lds, 16, 0, 0);
}

// ============================================================
// memory-bound prep bodies
// ============================================================
// rpb[j][i][h] f32 -> rpbT[h][i][j'] f16 (scaled log2e), j' permuted
// within each 64-block; [16][16][64] XOR-swizzled tile = exactly 32 KB.
__device__ void rpbT3_body(char* smem, int gxi, int gyj,
                           const float* rpb, f16* rpbT)
{
    f16* Lt = (f16*)smem;                 // flat [16 h][16 i][64 j-swz]
    const int t = threadIdx.x, wid = t >> 6, l = t & 63;
    const int i0 = gxi * 16;
    const int j0 = gyj * 64;
    const int il = l >> 2;
    const int h0 = (l & 3) * 4;
    const int swz = (il & 7) << 3;
#pragma unroll
    for (int p = 0; p < 16; ++p) {
        int jl = p * 4 + wid;
        float4 v = *reinterpret_cast<const float4*>(
            rpb + ((size_t)(j0 + jl) * SS + i0 + il) * HH + h0);
        int js = jl ^ swz;
        Lt[((h0 + 0) * 16 + il) * 64 + js] = (f16)(v.x * LOG2E);
        Lt[((h0 + 1) * 16 + il) * 64 + js] = (f16)(v.y * LOG2E);
        Lt[((h0 + 2) * 16 + il) * 64 + js] = (f16)(v.z * LOG2E);
        Lt[((h0 + 3) * 16 + il) * 64 + js] = (f16)(v.w * LOG2E);
    }
    __syncthreads();
    const int part = t & 7;
#pragma unroll
    for (int p = 0; p < 8; ++p) {
        int rowid = p * 32 + (t >> 3);
        int h = rowid >> 4, i2 = rowid & 15;
        int rsw = (i2 & 7) << 3;
        const f16* rowp = Lt + (h * 16 + i2) * 64;
        half8 v;
#pragma unroll
        for (int e = 0; e < 8; ++e) {
            int sig = 32 * (part & 1) + 16 * (e >> 2) + 4 * (part >> 1) + (e & 3);
            v[e] = rowp[sig ^ rsw];
        }
        *reinterpret_cast<half8*>(
            rpbT + ((size_t)h * SS + i0 + i2) * SS + j0 + part * 8) = v;
    }
}

__device__ void maskbits_body(int gx, const int* mask, u64* mb)
{
    const int t = threadIdx.x, wid = t >> 6, l = t & 63;
    const int row = gx * 4 + wid;     // b*SS+i
    const int* src = mask + (size_t)row * SS;
    u64* dst = mb + (size_t)row * 32;
    for (int it = 0; it < 32; ++it) {
        int mv = src[it * 64 + l];
        u64 bal = __ballot(mv != 0);
        if (l == 0) dst[it] = bal;
    }
}

// ============================================================
// prep_mem: ALL memory-bound prep in ONE launch at full BW —
// rpbT3 (4096) + cvt_x (6144) + cvt_wT (1024) + maskbits (1024)
// = 12288 blocks, ~533 MB total traffic, no compute blocks
// stealing CU slots.
// ============================================================
__global__ __launch_bounds__(256)
void prep_mem(const float* __restrict__ q, const float* __restrict__ k,
              const float* __restrict__ v, f16* __restrict__ oq,
              f16* __restrict__ ok, f16* __restrict__ ov,
              const float* __restrict__ wq, const float* __restrict__ wk,
              const float* __restrict__ wv, const float* __restrict__ wo,
              f16* __restrict__ owq, f16* __restrict__ owk,
              f16* __restrict__ owv, f16* __restrict__ owo,
              const float* __restrict__ rpb, f16* __restrict__ rpbT,
              const int* __restrict__ mask, u64* __restrict__ mbits)
{
    __shared__ __align__(16) char smem[32768];
    const int bid = blockIdx.x;
    const int t = threadIdx.x;
    if (bid < 4096) {
        rpbT3_body(smem, bid % 128, bid / 128, rpb, rpbT);
    } else if (bid < 4096 + 6144) {
        const int r = bid - 4096;
        const int z = r / 2048, bx = r % 2048;
        const float* src = z == 0 ? q : z == 1 ? k : v;
        f16* dst = z == 0 ? oq : z == 1 ? ok : ov;
        size_t i = ((size_t)bx * 256 + t) * 8;
        float4 v0 = *reinterpret_cast<const float4*>(src + i);
        float4 v1 = *reinterpret_cast<const float4*>(src + i + 4);
        half8 h;
        h[0] = (f16)v0.x; h[1] = (f16)v0.y; h[2] = (f16)v0.z; h[3] = (f16)v0.w;
        h[4] = (f16)v1.x; h[5] = (f16)v1.y; h[6] = (f16)v1.z; h[7] = (f16)v1.w;
        *reinterpret_cast<half8*>(dst + i) = h;
    } else if (bid < 4096 + 6144 + 1024) {
        const int r = bid - (4096 + 6144);
        const int z = r / 256;
        const int bx = r % 16, by = (r / 16) % 16;
        const float* W = z == 0 ? wq : z == 1 ? wk : z == 2 ? wv : wo;
        f16* WT = z == 0 ? owq : z == 1 ? owk : z == 2 ? owv : owo;
        float (*Lt)[65] = (float (*)[65])smem;
        const int n0 = bx * 64, k0 = by * 64;
        {
            int row = t >> 2;
            int c0  = (t & 3) * 16;
#pragma unroll
            for (int u = 0; u < 4; ++u) {
                float4 x = *reinterpret_cast<const float4*>(
                    &W[(size_t)(k0 + row) * DD + n0 + c0 + u * 4]);
                Lt[row][c0 + u * 4 + 0] = x.x;
                Lt[row][c0 + u * 4 + 1] = x.y;
                Lt[row][c0 + u * 4 + 2] = x.z;
                Lt[row][c0 + u * 4 + 3] = x.w;
            }
        }
        __syncthreads();
        {
            int n  = t >> 2;
            int kc = (t & 3) * 16;
            half8 h0, h1;
#pragma unroll
            for (int u = 0; u < 8; ++u) h0[u] = (f16)Lt[kc + u][n];
#pragma unroll
            for (int u = 0; u < 8; ++u) h1[u] = (f16)Lt[kc + 8 + u][n];
            f16* dst = &WT[(size_t)(n0 + n) * DD + k0 + kc];
            *reinterpret_cast<half8*>(dst) = h0;
            *reinterpret_cast<half8*>(dst + 8) = h1;
        }
    } else {
        maskbits_body(bid - (4096 + 6144 + 1024), mask, mbits);
    }
}

// ============================================================
// proj3 STANDALONE (768 blocks, full occupancy): software-pipelined
// K-loop (R16) + LDS-transposed coalesced epilogue (R15).
//   gz=0: Q = (query@Wq + bq)*0.125*log2e -> f16 [bh][s][64]
//   gz=1: K                               -> f16 [bh][s][64]
//   gz=2: V^T = (value@Wv + bv)^T         -> f16 [bh][d][s]
// ============================================================
__global__ __launch_bounds__(256)
void proj3(const f16* __restrict__ Xq, const f16* __restrict__ Xk,
           const f16* __restrict__ Xv, const f16* __restrict__ WqT,
           const f16* __restrict__ WkT, const f16* __restrict__ WvT,
           const float* __restrict__ bq, const float* __restrict__ bk,
           const float* __restrict__ bv,
           f16* __restrict__ Qo, f16* __restrict__ Ko, f16* __restrict__ VTo)
{
    __shared__ __align__(16) char smem[32768];
    char* AsB = smem;
    char* BsB = smem + 128 * 64 * 2;
    const int gx = blockIdx.x, gy = blockIdx.y, gz = blockIdx.z;
    const int t = threadIdx.x, wid = t >> 6, l = t & 63, c = l & 15, g = l >> 4;
    const f16 *Ap, *Bp; const float* bias; int m0, n0;
    if (gz == 2) { Ap = WvT; Bp = Xv; bias = bv; m0 = gx * 128; n0 = gy * 128; }
    else if (gz == 1) { Ap = Xk; Bp = WkT; bias = bk; m0 = gy * 128; n0 = gx * 128; }
    else { Ap = Xq; Bp = WqT; bias = bq; m0 = gy * 128; n0 = gx * 128; }
    const int wm = wid >> 1, wn = wid & 1;
    f32x4 acc[4][4] = {};

    const int s  = l & 7;
    const int r0 = wid * 32 + (l >> 3);
    const int sdst = (s << 4) ^ ((r0 & 7) << 4);

    half8 aN[4], bN[4];
#pragma unroll
    for (int j = 0; j < 4; ++j) {
        int row = r0 + j * 8;
        aN[j] = *(const half8*)(Ap + (size_t)(m0 + row) * DD + s * 8);
        bN[j] = *(const half8*)(Bp + (size_t)(n0 + row) * DD + s * 8);
    }
#pragma unroll
    for (int j = 0; j < 4; ++j) {
        int row = r0 + j * 8;
        *(half8*)(AsB + row * 128 + sdst) = aN[j];
        *(half8*)(BsB + row * 128 + sdst) = bN[j];
    }
    __syncthreads();

    for (int k0 = 0; k0 < DD; k0 += 64) {
        const bool more = (k0 + 64 < DD);
        const int kn = more ? k0 + 64 : 0;
#pragma unroll
        for (int j = 0; j < 4; ++j) {
            int row = r0 + j * 8;
            aN[j] = *(const half8*)(Ap + (size_t)(m0 + row) * DD + kn + s * 8);
            bN[j] = *(const half8*)(Bp + (size_t)(n0 + row) * DD + kn + s * 8);
        }
        __builtin_amdgcn_s_setprio(1);
#pragma unroll
        for (int ks = 0; ks < 2; ++ks) {
            half8 af[4];
#pragma unroll
            for (int mt = 0; mt < 4; ++mt) {
                int row = wm * 64 + mt * 16 + c;
                af[mt] = *(const half8*)(AsB + row * 128 +
                         ((ks * 64 + g * 16) ^ ((row & 7) << 4)));
            }
#pragma unroll
            for (int nt = 0; nt < 4; ++nt) {
                int row = wn * 64 + nt * 16 + c;
                half8 bf = *(const half8*)(BsB + row * 128 +
                           ((ks * 64 + g * 16) ^ ((row & 7) << 4)));
#pragma unroll
                for (int mt = 0; mt < 4; ++mt)
                    acc[mt][nt] = __builtin_amdgcn_mfma_f32_16x16x32_f16(
                        af[mt], bf, acc[mt][nt], 0, 0, 0);
            }
        }
        __builtin_amdgcn_s_setprio(0);
        __syncthreads();
        if (more) {
#pragma unroll
            for (int j = 0; j < 4; ++j) {
                int row = r0 + j * 8;
                *(half8*)(AsB + row * 128 + sdst) = aN[j];
                *(half8*)(BsB + row * 128 + sdst) = bN[j];
            }
        }
        __syncthreads();
    }

    // epilogue: bias + convert, stash to LDS, coalesced half8 stores
    f16* Ls = (f16*)smem;
    const float post = (gz == 0) ? 0.125f * LOG2E : 1.0f;
    if (gz < 2) {
#pragma unroll
        for (int nt = 0; nt < 4; ++nt) {
            int col = wn * 64 + nt * 16 + c;
            float bn = bias[n0 + col];
#pragma unroll
            for (int mt = 0; mt < 4; ++mt)
#pragma unroll
                for (int reg = 0; reg < 4; ++reg) {
                    int row = wm * 64 + mt * 16 + 4 * g + reg;
                    Ls[row * 128 + (col ^ ((row & 7) << 3))] =
                        (f16)((acc[mt][nt][reg] + bn) * post);
                }
        }
    } else {
#pragma unroll
        for (int mt = 0; mt < 4; ++mt)
#pragma unroll
            for (int reg = 0; reg < 4; ++reg) {
                int row = wm * 64 + mt * 16 + 4 * g + reg;
                float bd = bias[m0 + row];
#pragma unroll
                for (int nt = 0; nt < 4; ++nt) {
                    int col = wn * 64 + nt * 16 + c;
                    Ls[row * 128 + (col ^ ((row & 7) << 3))] =
                        (f16)(acc[mt][nt][reg] + bd);
                }
            }
    }
    __syncthreads();
#pragma unroll
    for (int e = 0; e < 8; ++e) {
        int fi = e * 256 + t;
        int row = fi >> 4;
        int col0 = (fi & 15) * 8;
        half8 v = *reinterpret_cast<const half8*>(
            Ls + row * 128 + (col0 ^ ((row & 7) << 3)));
        if (gz < 2) {
            f16* dst = gz ? Ko : Qo;
            int m = m0 + row, n = n0 + col0;
            int b = m >> 11, sdx = m & (SS - 1);
            int h = n >> 6, hd = n & 63;
            *reinterpret_cast<half8*>(
                &dst[(((size_t)(b * HH + h)) * SS + sdx) * 64 + hd]) = v;
        } else {
            int m = m0 + row, n = n0 + col0;
            int h = m >> 6, dl = m & 63;
            int b = n >> 11;
            *reinterpret_cast<half8*>(
                &VTo[(((size_t)(b * HH + h)) * 64 + dl) * SS + (n & (SS - 1))]) = v;
        }
    }
}

// ============================================================
// Flash attention (R8/R10 version): swapped QK^T, lane-local softmax,
// in-register P, QBLK=64, 4 blocks/CU, one barrier/iter. LDS 32 KB.
// ============================================================
__global__ __launch_bounds__(256, 4)
void attn_fwd(const f16* __restrict__ Qw, const f16* __restrict__ Kw,
              const f16* __restrict__ VTw, const f16* __restrict__ rpbT,
              const u64* __restrict__ mbits, f16* __restrict__ AOh)
{
    __shared__ f16 Ks[2][64 * 64];
    __shared__ f16 Vs[2][64 * 64];

    const int t = threadIdx.x, wid = t >> 6, l = t & 63, c = l & 15, g = l >> 4;
    const int bh = blockIdx.x, b = bh >> 4, h = bh & 15;
    const int q0 = blockIdx.y * 64;
    const size_t baseSD = (size_t)bh * SS * 64;
    const size_t baseDS = (size_t)bh * 64 * SS;
    const f16* Kbase = Kw + baseSD;
    const f16* Vbase = VTw + baseDS;

    const int qrow_c = q0 + wid * 16 + c;
    const f16* bp = rpbT + (size_t)h * SS * SS + (size_t)qrow_c * SS + g * 16;
    const u64* mp = mbits + ((size_t)b * SS + qrow_c) * 32;

    const int s     = l & 7;
    const int srow0 = wid * 16 + (l >> 3);
    const int sswz  = (srow0 & 7) << 4;
    const int kdst  = (s << 4) ^ sswz;
    const int velo  = 32 * (s >> 2) + 16 * (s & 1) + 4 * ((s >> 1) & 1);
    const int vdlo  = (velo * 2) ^ sswz;
    const int vdhi  = (velo * 2 + 16) ^ sswz;

    int ga[4];
#pragma unroll
    for (int r = 0; r < 4; ++r) ga[r] = (g * 4 + r) * 4;

    half8 qf[2];
    qf[0] = *(const half8*)(Qw + baseSD + (size_t)qrow_c * 64 + g * 8);
    qf[1] = *(const half8*)(Qw + baseSD + (size_t)qrow_c * 64 + 32 + g * 8);

    // ---- prologue: stage tile 0 ----
    {
        half8 k0 = *(const half8*)(Kbase + (size_t)srow0 * 64 + s * 8);
        half8 k1 = *(const half8*)(Kbase + (size_t)(srow0 + 8) * 64 + s * 8);
        half8 v0 = *(const half8*)(Vbase + (size_t)srow0 * SS + s * 8);
        half8 v1 = *(const half8*)(Vbase + (size_t)(srow0 + 8) * SS + s * 8);
        char* kd = (char*)Ks[0]; char* vd = (char*)Vs[0];
        *(half8*)(kd + srow0 * 128 + kdst) = k0;
        *(half8*)(kd + (srow0 + 8) * 128 + kdst) = k1;
        half4 lo0 = {v0[0], v0[1], v0[2], v0[3]}, hi0 = {v0[4], v0[5], v0[6], v0[7]};
        half4 lo1 = {v1[0], v1[1], v1[2], v1[3]}, hi1 = {v1[4], v1[5], v1[6], v1[7]};
        *(half4*)(vd + srow0 * 128 + vdlo) = lo0;
        *(half4*)(vd + srow0 * 128 + vdhi) = hi0;
        *(half4*)(vd + (srow0 + 8) * 128 + vdlo) = lo1;
        *(half4*)(vd + (srow0 + 8) * 128 + vdhi) = hi1;
    }
    half8 bb0 = *(const half8*)(bp);
    half8 bb1 = *(const half8*)(bp + 8);
    u64 mm = mp[0];
    __syncthreads();

    f32x4 acc[4] = {};
    float mrow = -INFINITY, lp = 0.f;
    const int shg = 4 * g;

    int buf = 0;
    for (int kt = 0; kt < SS / 64; ++kt) {
        const bool more = (kt + 1 < SS / 64);
        const int jn = more ? (kt + 1) * 64 : 0;
        const int ktn = more ? kt + 1 : 0;

        half8 k0n = *(const half8*)(Kbase + (size_t)(jn + srow0) * 64 + s * 8);
        half8 k1n = *(const half8*)(Kbase + (size_t)(jn + srow0 + 8) * 64 + s * 8);
        half8 v0n = *(const half8*)(Vbase + (size_t)srow0 * SS + jn + s * 8);
        half8 v1n = *(const half8*)(Vbase + (size_t)(srow0 + 8) * SS + jn + s * 8);
        half8 bbn0 = *(const half8*)(bp + jn);
        half8 bbn1 = *(const half8*)(bp + jn + 8);
        u64 mmn = mp[ktn];

        char* KsB = (char*)Ks[buf];
        char* VsB = (char*)Vs[buf];

        u64 sh = mm >> shg;
        f32x4 sc[4];
#pragma unroll
        for (int nt = 0; nt < 4; ++nt)
#pragma unroll
            for (int r = 0; r < 4; ++r) {
                float bf = (float)(nt < 2 ? bb0[nt * 4 + r] : bb1[(nt - 2) * 4 + r]);
                sc[nt][r] = ((sh >> (16 * nt + r)) & 1) ? bf : MASKNEG;
            }

        __builtin_amdgcn_s_setprio(1);
#pragma unroll
        for (int ks = 0; ks < 2; ++ks)
#pragma unroll
            for (int nt = 0; nt < 4; ++nt) {
                int row = nt * 16 + c;
                half8 kf = *(const half8*)(KsB + row * 128 +
                           ((ks * 64 + g * 16) ^ ((row & 7) << 4)));
                sc[nt] = __builtin_amdgcn_mfma_f32_16x16x32_f16(
                    kf, qf[ks], sc[nt], 0, 0, 0);
            }
        __builtin_amdgcn_s_setprio(0);

        float rm = fmaxf(fmaxf(fmaxf(sc[0][0], sc[0][1]), fmaxf(sc[0][2], sc[0][3])),
                         fmaxf(fmaxf(sc[1][0], sc[1][1]), fmaxf(sc[1][2], sc[1][3])));
        rm = fmaxf(rm, fmaxf(fmaxf(fmaxf(sc[2][0], sc[2][1]), fmaxf(sc[2][2], sc[2][3])),
                             fmaxf(fmaxf(sc[3][0], sc[3][1]), fmaxf(sc[3][2], sc[3][3]))));
        rm = fmaxf(rm, __shfl_xor(rm, 16));
        rm = fmaxf(rm, __shfl_xor(rm, 32));
        if (!__all(rm <= mrow + 8.0f)) {
            float mn = fmaxf(mrow, rm);
            float scal = exp2f(mrow - mn);
            mrow = mn;
            lp *= scal;
            float sq[4];
#pragma unroll
            for (int r = 0; r < 4; ++r)
                sq[r] = __int_as_float(__builtin_amdgcn_ds_bpermute(
                            ga[r], __float_as_int(scal)));
#pragma unroll
            for (int nt = 0; nt < 4; ++nt)
#pragma unroll
                for (int r = 0; r < 4; ++r) acc[nt][r] *= sq[r];
        }
        float psum = 0.f;
#pragma unroll
        for (int nt = 0; nt < 4; ++nt)
#pragma unroll
            for (int r = 0; r < 4; ++r) {
                float p = exp2f(sc[nt][r] - mrow);
                sc[nt][r] = p;
                psum += p;
            }
        lp += psum;

        half4 pa[4];
#pragma unroll
        for (int kk = 0; kk < 4; ++kk) {
            half4 pv = {(f16)sc[kk][0], (f16)sc[kk][1],
                        (f16)sc[kk][2], (f16)sc[kk][3]};
            pa[kk] = pv;
        }

        __builtin_amdgcn_s_setprio(1);
#pragma unroll
        for (int ks = 0; ks < 2; ++ks)
#pragma unroll
            for (int nt2 = 0; nt2 < 4; ++nt2) {
                int row = nt2 * 16 + c;
                half8 vf = *(const half8*)(VsB + row * 128 +
                           ((ks * 64 + g * 16) ^ ((row & 7) << 4)));
                half4 vlo = {vf[0], vf[1], vf[2], vf[3]};
                half4 vhi = {vf[4], vf[5], vf[6], vf[7]};
                acc[nt2] = __builtin_amdgcn_mfma_f32_16x16x16f16(
                    pa[2 * ks], vlo, acc[nt2], 0, 0, 0);
                acc[nt2] = __builtin_amdgcn_mfma_f32_16x16x16f16(
                    pa[2 * ks + 1], vhi, acc[nt2], 0, 0, 0);
            }
        __builtin_amdgcn_s_setprio(0);

        if (more) {
            char* kd = (char*)Ks[buf ^ 1];
            char* vd = (char*)Vs[buf ^ 1];
            *(half8*)(kd + srow0 * 128 + kdst) = k0n;
            *(half8*)(kd + (srow0 + 8) * 128 + kdst) = k1n;
            half4 lo0 = {v0n[0], v0n[1], v0n[2], v0n[3]}, hi0 = {v0n[4], v0n[5], v0n[6], v0n[7]};
            half4 lo1 = {v1n[0], v1n[1], v1n[2], v1n[3]}, hi1 = {v1n[4], v1n[5], v1n[6], v1n[7]};
            *(half4*)(vd + srow0 * 128 + vdlo) = lo0;
            *(half4*)(vd + srow0 * 128 + vdhi) = hi0;
            *(half4*)(vd + (srow0 + 8) * 128 + vdlo) = lo1;
            *(half4*)(vd + (srow0 + 8) * 128 + vdhi) = hi1;
            buf ^= 1;
            bb0 = bbn0; bb1 = bbn1; mm = mmn;
        }
        __syncthreads();
    }

    float lt = lp;
    lt += __shfl_xor(lt, 16);
    lt += __shfl_xor(lt, 32);
    float linv[4];
#pragma unroll
    for (int r = 0; r < 4; ++r)
        linv[r] = 1.0f / __int_as_float(__builtin_amdgcn_ds_bpermute(
                      ga[r], __float_as_int(lt)));
#pragma unroll
    for (int r = 0; r < 4; ++r) {
        int qrow = q0 + wid * 16 + 4 * g + r;
#pragma unroll
        for (int nt2 = 0; nt2 < 4; ++nt2)
            AOh[((size_t)b * SS + qrow) * DD + h * 64 + nt2 * 16 + c] =
                (f16)(acc[nt2][r] * linv[r]);
    }
}

// ============================================================
// Output projection: out(f32) = AO(f16) @ Wo + bo.
// ============================================================
__global__ __launch_bounds__(256)
void gemm_out(const f16* __restrict__ A, const f16* __restrict__ BT,
              const float* __restrict__ bias, float* __restrict__ out)
{
    __shared__ f16 As[128 * 64];
    __shared__ f16 Bs[128 * 64];
    const int t = threadIdx.x, wid = t >> 6, l = t & 63, c = l & 15, g = l >> 4;
    const int m0 = blockIdx.y * 128, n0 = blockIdx.x * 128;
    const int wm = wid >> 1, wn = wid & 1;
    f32x4 acc[4][4] = {};
    char* AsB = (char*)As; char* BsB = (char*)Bs;

    for (int k0 = 0; k0 < DD; k0 += 64) {
        __syncthreads();
#pragma unroll
        for (int j = 0; j < 4; ++j) {
            int row = wid * 32 + j * 8 + (l >> 3);
            int slot = (l & 7) ^ (row & 7);
            gload16(A + (size_t)(m0 + row) * DD + k0 + slot * 8,
                    AsB + (wid * 32 + j * 8) * 128);
            gload16(BT + (size_t)(n0 + row) * DD + k0 + slot * 8,
                    BsB + (wid * 32 + j * 8) * 128);
        }
        __syncthreads();
#pragma unroll
        for (int ks = 0; ks < 2; ++ks) {
            half8 af[4];
#pragma unroll
            for (int mt = 0; mt < 4; ++mt) {
                int row = wm * 64 + mt * 16 + c;
                af[mt] = *(const half8*)(AsB + row * 128 +
                         ((ks * 64 + g * 16) ^ ((row & 7) << 4)));
            }
#pragma unroll
            for (int nt = 0; nt < 4; ++nt) {
                int row = wn * 64 + nt * 16 + c;
                half8 bf = *(const half8*)(BsB + row * 128 +
                           ((ks * 64 + g * 16) ^ ((row & 7) << 4)));
#pragma unroll
                for (int mt = 0; mt < 4; ++mt)
                    acc[mt][nt] = __builtin_amdgcn_mfma_f32_16x16x32_f16(
                        af[mt], bf, acc[mt][nt], 0, 0, 0);
            }
        }
    }
#pragma unroll
    for (int nt = 0; nt < 4; ++nt) {
        int n = n0 + wn * 64 + nt * 16 + c;
        float bn = bias[n];
#pragma unroll
        for (int mt = 0; mt < 4; ++mt)
#pragma unroll
            for (int reg = 0; reg < 4; ++reg) {
                int m = m0 + wm * 64 + mt * 16 + 4 * g + reg;
                out[(size_t)m * DD + n] = acc[mt][nt][reg] + bn;
            }
    }
}

extern "C" void kernel_launch(void* const* d_in, const int* in_sizes, int n_in,
                              void* d_out, int out_size, void* d_ws, size_t ws_size,
                              hipStream_t stream)
{
    (void)in_sizes; (void)n_in; (void)out_size; (void)ws_size;

    const float* query = (const float*)d_in[0];
    const float* key   = (const float*)d_in[1];
    const float* value = (const float*)d_in[2];
    const int*   mask  = (const int*)d_in[3];
    const float* rpb   = (const float*)d_in[4];
    const float* Wq = (const float*)d_in[5];  const float* bq = (const float*)d_in[6];
    const float* Wk = (const float*)d_in[7];  const float* bk = (const float*)d_in[8];
    const float* Wv = (const float*)d_in[9];  const float* bv = (const float*)d_in[10];
    const float* Wo = (const float*)d_in[11]; const float* bo = (const float*)d_in[12];
    float* out = (float*)d_out;

    // workspace layout (f16 elements). AOh aliases Xq (dead after proj3).
    const size_t NX = (size_t)2 * SS * DD;   // 4096x1024
    const size_t NW = (size_t)DD * DD;       // 1024x1024
    f16* Xq    = (f16*)d_ws;
    f16* Xk    = Xq + NX;
    f16* Xv    = Xk + NX;
    f16* WqT   = Xv + NX;
    f16* WkT   = WqT + NW;
    f16* WvT   = WkT + NW;
    f16* WoT   = WvT + NW;
    f16* Qw    = WoT + NW;
    f16* Kw    = Qw + NX;
    f16* VTw   = Kw + NX;
    f16* rpbT  = VTw + NX;                   // 16*2048*2048 f16 = 128 MB
    u64* mbits = (u64*)(rpbT + (size_t)HH * SS * SS);  // 1 MB
    f16* AOh   = Xq;   // alias

    prep_mem<<<dim3(12288), 256, 0, stream>>>(query, key, value, Xq, Xk, Xv,
                                              Wq, Wk, Wv, Wo, WqT, WkT, WvT, WoT,
                                              rpb, rpbT, mask, mbits);
    proj3<<<dim3(8, 32, 3), 256, 0, stream>>>(Xq, Xk, Xv, WqT, WkT, WvT,
                                              bq, bk, bv, Qw, Kw, VTw);
    attn_fwd<<<dim3(2 * HH, SS / 64), 256, 0, stream>>>(Qw, Kw, VTw, rpbT, mbits, AOh);
    gemm_out<<<dim3(8, 32), 256, 0, stream>>>(AOh, WoT, bo, out);
}